// Round 1
// baseline (1899.513 us; speedup 1.0000x reference)
//
#include <hip/hip_runtime.h>
#include <stdint.h>

typedef unsigned int uint;
typedef unsigned short ushort;

// bf16 helpers: pack two bf16 in a uint, lo = even index, hi = odd index
__device__ __forceinline__ float bflo(uint u){ return __uint_as_float(u << 16); }
__device__ __forceinline__ float bfhi(uint u){ return __uint_as_float(u & 0xffff0000u); }
__device__ __forceinline__ ushort f2bf(float f){
  uint u = __float_as_uint(f);
  return (ushort)((u + 0x7fffu + ((u >> 16) & 1u)) >> 16);   // round-nearest-even
}

// ---------------------------------------------------------------------------
// mu[v][p] = relu(th1[p][0]*s_v + th1[p][1]*t_v + dot(th2[p,:], x[v,:])/||x_v||)
// wave per node; lane l owns outputs p=2l, 2l+1. x row held 2 floats/lane,
// broadcast via readlane-shuffles; th2 staged bf16 in LDS as [k][p].
// ---------------------------------------------------------------------------
__global__ __launch_bounds__(256) void k_mu(
    const float* __restrict__ sv, const float* __restrict__ tv,
    const float* __restrict__ x, const float* __restrict__ th1,
    const float* __restrict__ th2, uint* __restrict__ mu_u, int n)
{
  __shared__ ushort t2[128*128];  // [k][p] = bf16(th2[p][k]), 32 KB
  const int tid = threadIdx.x;
  for (int i = tid; i < 128*128; i += 256) {
    int k = i >> 7, p = i & 127;
    t2[i] = f2bf(th2[p*128 + k]);        // LDS writes consecutive: conflict-free
  }
  __syncthreads();
  const uint* t2u = (const uint*)t2;     // [k*64 + l] -> (p=2l lo, p=2l+1 hi)
  const int wv = tid >> 6, l = tid & 63;
  for (int v = blockIdx.x*4 + wv; v < n; v += gridDim.x*4) {
    float2 xv = ((const float2*)(x + (size_t)v*128))[l];
    float ss = xv.x*xv.x + xv.y*xv.y;
    #pragma unroll
    for (int off = 32; off > 0; off >>= 1) ss += __shfl_down(ss, off, 64);
    ss = __shfl(ss, 0, 64);
    float inv = (ss > 0.f) ? rsqrtf(ss) : 1.0f;
    float d0 = 0.f, d1 = 0.f;
    #pragma unroll 8
    for (int k2 = 0; k2 < 64; ++k2) {
      float a0 = __shfl(xv.x, k2, 64);   // xn[2*k2]   (pre-norm; scale at end)
      float a1 = __shfl(xv.y, k2, 64);   // xn[2*k2+1]
      uint w0 = t2u[(2*k2)*64 + l];
      uint w1 = t2u[(2*k2+1)*64 + l];
      d0 += a0*bflo(w0) + a1*bflo(w1);
      d1 += a0*bfhi(w0) + a1*bfhi(w1);
    }
    float4 t1 = ((const float4*)th1)[l];  // rows 2l (x,y) and 2l+1 (z,w)
    float s = sv[v], t = tv[v];
    float m0 = fmaxf(t1.x*s + t1.y*t + d0*inv, 0.f);
    float m1 = fmaxf(t1.z*s + t1.w*t + d1*inv, 0.f);
    mu_u[(size_t)v*64 + l] = ((uint)f2bf(m1) << 16) | (uint)f2bf(m0);
  }
}

// ------------------------------- CSR build ---------------------------------
__global__ void k_count(const int* __restrict__ src, int* __restrict__ cnt, int e) {
  int i = blockIdx.x*256 + threadIdx.x;
  if (i < e) atomicAdd(&cnt[src[i]], 1);
}

__global__ __launch_bounds__(256) void k_scan1(const int* __restrict__ cnt,
    int* __restrict__ excl, int* __restrict__ bsum, int n) {
  __shared__ int tmp[256];
  int tid = threadIdx.x;
  int i = blockIdx.x*256 + tid;
  int c = (i < n) ? cnt[i] : 0;
  tmp[tid] = c; __syncthreads();
  for (int off = 1; off < 256; off <<= 1) {
    int t = (tid >= off) ? tmp[tid - off] : 0;
    __syncthreads();
    tmp[tid] += t;
    __syncthreads();
  }
  if (i < n) excl[i] = tmp[tid] - c;
  if (tid == 255) bsum[blockIdx.x] = tmp[255];
}

__global__ __launch_bounds__(512) void k_scan2(const int* __restrict__ bsum,
    int* __restrict__ bbase, int nb) {  // nb <= 512 (n=100k -> 391)
  __shared__ int tmp[512];
  int tid = threadIdx.x;
  int c = (tid < nb) ? bsum[tid] : 0;
  tmp[tid] = c; __syncthreads();
  for (int off = 1; off < 512; off <<= 1) {
    int t = (tid >= off) ? tmp[tid - off] : 0;
    __syncthreads();
    tmp[tid] += t;
    __syncthreads();
  }
  if (tid < nb) bbase[tid] = tmp[tid] - c;
}

__global__ void k_initcur(const int* __restrict__ excl, const int* __restrict__ bbase,
                          int* __restrict__ cursor, int n) {
  int i = blockIdx.x*256 + threadIdx.x;
  if (i < n) cursor[i] = excl[i] + bbase[i >> 8];
}

__global__ void k_scatter(const int* __restrict__ src, const int* __restrict__ dst,
                          int* __restrict__ cursor, int* __restrict__ sorted, int e) {
  int i = blockIdx.x*256 + threadIdx.x;
  if (i < e) {
    int p = atomicAdd(&cursor[src[i]], 1);
    sorted[p] = dst[i];
  }
}

// ---------------------------------------------------------------------------
// Per node v (one wave): nb = sum_{u in N(v)} mu_u[u]; s = deg*mu - nb;
// mu'[v] = h_theta @ [mu ; relu(s)].  h staged bf16 LDS [j][p] (exactly 64 KB).
// Inputs broadcast from lane registers via shuffles (no LDS in-buffer).
// ---------------------------------------------------------------------------
__global__ __launch_bounds__(256) void k_gmlp(
    const uint* __restrict__ mu_u, const int* __restrict__ sorted,
    const int* __restrict__ cnt, const int* __restrict__ excl,
    const int* __restrict__ bbase, const float* __restrict__ h_theta,
    float* __restrict__ mu_p, int n)
{
  __shared__ ushort hT[256*128];   // [j][p] = bf16(h_theta[p][j]), 64 KB
  const int tid = threadIdx.x;
  for (int i = tid; i < 256*128; i += 256) {
    int j = i >> 7, p = i & 127;
    hT[i] = f2bf(h_theta[p*256 + j]);
  }
  __syncthreads();
  const uint* hTu = (const uint*)hT;  // [j*64 + l]
  const int wv = tid >> 6, l = tid & 63;
  for (int v = blockIdx.x*4 + wv; v < n; v += gridDim.x*4) {
    int deg = cnt[v];
    int start = excl[v] + bbase[v >> 8];
    float nb0 = 0.f, nb1 = 0.f;
    for (int base = 0; base < deg; base += 64) {
      int m = min(deg - base, 64);
      int idx = (l < m) ? sorted[start + base + l] : 0;
      #pragma unroll 8
      for (int j = 0; j < m; ++j) {
        int d = __shfl(idx, j, 64);
        uint u = mu_u[(size_t)d*64 + l];   // wave reads 256 B row (L2/L3)
        nb0 += bflo(u); nb1 += bfhi(u);
      }
    }
    uint um = mu_u[(size_t)v*64 + l];
    float m0 = bflo(um), m1 = bfhi(um);
    float dg = (float)deg;
    float s0 = fmaxf(dg*m0 - nb0, 0.f);
    float s1 = fmaxf(dg*m1 - nb1, 0.f);
    float o0 = 0.f, o1 = 0.f;
    #pragma unroll 8
    for (int q = 0; q < 64; ++q) {        // j = 2q, 2q+1 (mu half)
      float a0 = __shfl(m0, q, 64);
      float a1 = __shfl(m1, q, 64);
      uint w0 = hTu[(2*q)*64 + l];
      uint w1 = hTu[(2*q+1)*64 + l];
      o0 += a0*bflo(w0) + a1*bflo(w1);
      o1 += a0*bfhi(w0) + a1*bfhi(w1);
    }
    #pragma unroll 8
    for (int q = 0; q < 64; ++q) {        // j = 128+2q, 128+2q+1 (relu(s) half)
      float a0 = __shfl(s0, q, 64);
      float a1 = __shfl(s1, q, 64);
      uint w0 = hTu[(128 + 2*q)*64 + l];
      uint w1 = hTu[(129 + 2*q)*64 + l];
      o0 += a0*bflo(w0) + a1*bflo(w1);
      o1 += a0*bfhi(w0) + a1*bfhi(w1);
    }
    ((float2*)(mu_p + (size_t)v*128))[l] = make_float2(o0, o1);
  }
}

// sum over nodes of mu_prime columns -> gsum[128]
__global__ __launch_bounds__(256) void k_colsum(const float* __restrict__ mu_p,
    float* __restrict__ gsum, int n) {
  int tid = threadIdx.x;
  int p = tid & 127, half = tid >> 7;
  float acc = 0.f;
  for (int v = blockIdx.x*2 + half; v < n; v += gridDim.x*2)
    acc += mu_p[(size_t)v*128 + p];
  atomicAdd(&gsum[p], acc);
}

// up = th4 @ gsum; C = sum_p th3[p]*relu(up[p])
__global__ __launch_bounds__(128) void k_upC(const float* __restrict__ gsum,
    const float* __restrict__ th4, const float* __restrict__ th3,
    float* __restrict__ Cbuf) {
  __shared__ float S[128];
  __shared__ float part[128];
  int tid = threadIdx.x;
  S[tid] = gsum[tid];
  __syncthreads();
  float up = 0.f;
  const float4* r4 = (const float4*)(th4 + tid*128);
  const float4* S4 = (const float4*)S;
  #pragma unroll 8
  for (int q = 0; q < 32; ++q) {
    float4 w = r4[q], a = S4[q];
    up += w.x*a.x + w.y*a.y + w.z*a.z + w.w*a.w;
  }
  float r = th3[tid] * fmaxf(up, 0.f);
  part[tid] = r; __syncthreads();
  if (tid < 64) part[tid] += part[tid + 64];
  __syncthreads();
  if (tid < 64) {
    float v = part[tid];
    #pragma unroll
    for (int off = 32; off > 0; off >>= 1) v += __shfl_down(v, off, 64);
    if (tid == 0) Cbuf[0] = v;
  }
}

// out[v] = C + sum_p th3[128+p]*relu( sum_q th5[p][q]*mu_p[v][q] )
__global__ __launch_bounds__(256) void k_final(
    const float* __restrict__ mu_p, const float* __restrict__ th5,
    const float* __restrict__ th3, const float* __restrict__ Cbuf,
    float* __restrict__ out, int n)
{
  __shared__ ushort t5[128*128];   // [q][p] = bf16(th5[p][q]), 32 KB
  const int tid = threadIdx.x;
  for (int i = tid; i < 128*128; i += 256) {
    int q = i >> 7, p = i & 127;
    t5[i] = f2bf(th5[p*128 + q]);
  }
  __syncthreads();
  const uint* t5u = (const uint*)t5;
  const int wv = tid >> 6, l = tid & 63;
  const float C = Cbuf[0];
  const float2 t3 = ((const float2*)(th3 + 128))[l];  // th3[128+2l], th3[129+2l]
  for (int v = blockIdx.x*4 + wv; v < n; v += gridDim.x*4) {
    float2 in = ((const float2*)(mu_p + (size_t)v*128))[l];
    float o0 = 0.f, o1 = 0.f;
    #pragma unroll 8
    for (int q = 0; q < 64; ++q) {
      float a0 = __shfl(in.x, q, 64);
      float a1 = __shfl(in.y, q, 64);
      uint w0 = t5u[(2*q)*64 + l];
      uint w1 = t5u[(2*q+1)*64 + l];
      o0 += a0*bflo(w0) + a1*bflo(w1);
      o1 += a0*bfhi(w0) + a1*bfhi(w1);
    }
    float r = t3.x*fmaxf(o0, 0.f) + t3.y*fmaxf(o1, 0.f);
    #pragma unroll
    for (int off = 32; off > 0; off >>= 1) r += __shfl_down(r, off, 64);
    if (l == 0) out[v] = C + r;
  }
}

extern "C" void kernel_launch(void* const* d_in, const int* in_sizes, int n_in,
                              void* d_out, int out_size, void* d_ws, size_t ws_size,
                              hipStream_t stream)
{
  const float* sv  = (const float*)d_in[0];
  const float* tv  = (const float*)d_in[1];
  const float* x   = (const float*)d_in[2];
  const int*   esrc= (const int*)d_in[3];
  const int*   edst= (const int*)d_in[4];
  const float* th1 = (const float*)d_in[5];
  const float* th2 = (const float*)d_in[6];
  const float* th3 = (const float*)d_in[7];
  const float* th4 = (const float*)d_in[8];
  const float* th5 = (const float*)d_in[9];
  const float* hth = (const float*)d_in[10];
  float* out = (float*)d_out;
  const int n = in_sizes[0];
  const int e = in_sizes[3];

  // workspace carve (~91 MB)
  char* w = (char*)d_ws;
  auto carve = [&](size_t bytes) { char* p = w; w += (bytes + 255) & ~(size_t)255; return p; };
  float* mu_p   = (float*)carve((size_t)n*128*4);  // mu_prime f32
  uint*  mu_u   = (uint*) carve((size_t)n*64*4);   // mu bf16 packed
  int*   sorted = (int*)  carve((size_t)e*4);      // CSR adjacency (dst sorted by src)
  int*   cnt    = (int*)  carve((size_t)n*4);      // deg
  int*   excl   = (int*)  carve((size_t)n*4);
  int*   cursor = (int*)  carve((size_t)n*4);
  int*   bsum   = (int*)  carve(512*4);
  int*   bbase  = (int*)  carve(512*4);
  float* gsum   = (float*)carve(128*4);
  float* Cbuf   = (float*)carve(256);

  const int nb1 = (n + 255) >> 8;   // 391 for n=100000 (<=512 required by k_scan2)

  hipMemsetAsync(cnt, 0, (size_t)n*4, stream);
  hipMemsetAsync(gsum, 0, 128*4, stream);

  k_mu     <<<1024, 256, 0, stream>>>(sv, tv, x, th1, th2, mu_u, n);
  k_count  <<<(e + 255)/256, 256, 0, stream>>>(esrc, cnt, e);
  k_scan1  <<<nb1, 256, 0, stream>>>(cnt, excl, bsum, n);
  k_scan2  <<<1, 512, 0, stream>>>(bsum, bbase, nb1);
  k_initcur<<<nb1, 256, 0, stream>>>(excl, bbase, cursor, n);
  k_scatter<<<(e + 255)/256, 256, 0, stream>>>(esrc, edst, cursor, sorted, e);
  k_gmlp   <<<1024, 256, 0, stream>>>(mu_u, sorted, cnt, excl, bbase, hth, mu_p, n);
  k_colsum <<<128, 256, 0, stream>>>(mu_p, gsum, n);
  k_upC    <<<1, 128, 0, stream>>>(gsum, th4, th3, Cbuf);
  k_final  <<<1024, 256, 0, stream>>>(mu_p, th5, th3, Cbuf, out, n);
}

// Round 2
// 815.724 us; speedup vs baseline: 2.3286x; 2.3286x over previous
//
#include <hip/hip_runtime.h>
#include <stdint.h>

typedef unsigned int uint;
typedef unsigned short ushort;
typedef __attribute__((ext_vector_type(4))) float f32x4;
typedef __attribute__((ext_vector_type(8))) short bf16x8;   // 8 bf16 in 4 VGPRs

union U4H8 { uint4 u; bf16x8 h; };

__device__ __forceinline__ float bflo(uint u){ return __uint_as_float(u << 16); }
__device__ __forceinline__ float bfhi(uint u){ return __uint_as_float(u & 0xffff0000u); }
__device__ __forceinline__ ushort f2bf(float f){
  uint u = __float_as_uint(f);
  return (ushort)((u + 0x7fffu + ((u >> 16) & 1u)) >> 16);   // RNE
}
__device__ __forceinline__ uint pack2(float lo, float hi){
  return ((uint)f2bf(hi) << 16) | (uint)f2bf(lo);
}

// ---------------------------------------------------------------------------
// xn[v] = x[v] / ||x[v]||  -> bf16 packed row-major [N][128] (uint[N][64])
// ---------------------------------------------------------------------------
__global__ __launch_bounds__(256) void k_norm(const float* __restrict__ x,
    uint* __restrict__ xn_u, int n)
{
  int w = threadIdx.x >> 6, l = threadIdx.x & 63;
  for (int v = blockIdx.x*4 + w; v < n; v += gridDim.x*4) {
    float2 xv = ((const float2*)x)[(size_t)v*64 + l];
    float ss = xv.x*xv.x + xv.y*xv.y;
    #pragma unroll
    for (int off = 32; off > 0; off >>= 1) ss += __shfl_down(ss, off, 64);
    ss = __shfl(ss, 0, 64);
    float inv = (ss > 0.f) ? rsqrtf(ss) : 1.f;
    xn_u[(size_t)v*64 + l] = pack2(xv.x*inv, xv.y*inv);
  }
}

// ---------------------------------------------------------------------------
// MFMA GEMM #1: mu[v][p] = relu( (xn @ th2^T)[v][p] + th1[p][0]*sv + th1[p][1]*tv )
// Per-wave tile: 16 nodes x 128 cols, K=128. B (th2) staged as swizzled frags.
// Frag layouts (16x16x32): A: m=lane&15, k=(lane>>4)*8+j ; B: n=lane&15, same k.
// D: col=lane&15, row=(lane>>4)*4+reg  [measured m89/m91].
// ---------------------------------------------------------------------------
__global__ __launch_bounds__(256) void k_mu(
    const uint4* __restrict__ xn4, const float* __restrict__ sv,
    const float* __restrict__ tv, const float* __restrict__ th1,
    const float* __restrict__ th2, ushort* __restrict__ mu_s, int n)
{
  __shared__ uint4 B[2048];   // [s:4][t:8][lane:64], 32 KB
  const int tid = threadIdx.x;
  for (int f = tid; f < 2048; f += 256) {
    int l = f & 63, rest = f >> 6;          // rest: 0..31
    int s = rest >> 3, t = rest & 7;
    int row = t*16 + (l & 15);              // W row (output col p)
    int kb  = s*32 + (l >> 4)*8;
    const float* p = th2 + row*128 + kb;
    float4 a = *(const float4*)p;
    float4 b = *(const float4*)(p + 4);
    uint4 u; u.x = pack2(a.x,a.y); u.y = pack2(a.z,a.w);
    u.z = pack2(b.x,b.y); u.w = pack2(b.z,b.w);
    B[(s*8 + t)*64 + l] = u;
  }
  __syncthreads();
  const int w = tid >> 6, l = tid & 63, q = l >> 4, c = l & 15;
  float2 t1[8];
  #pragma unroll
  for (int t = 0; t < 8; ++t) t1[t] = ((const float2*)th1)[t*16 + c];
  const int ntiles = (n + 15) >> 4;
  for (int T = blockIdx.x*4 + w; T < ntiles; T += gridDim.x*4) {
    int v0 = T*16;
    int arow = min(v0 + c, n-1);
    U4H8 a[4];
    #pragma unroll
    for (int s = 0; s < 4; ++s) a[s].u = xn4[(size_t)arow*16 + s*4 + q];
    f32x4 acc[8];
    #pragma unroll
    for (int t = 0; t < 8; ++t) acc[t] = (f32x4){0.f,0.f,0.f,0.f};
    #pragma unroll
    for (int s = 0; s < 4; ++s) {
      #pragma unroll
      for (int t = 0; t < 8; ++t) {
        U4H8 b; b.u = B[(s*8 + t)*64 + l];
        acc[t] = __builtin_amdgcn_mfma_f32_16x16x32_bf16(a[s].h, b.h, acc[t], 0, 0, 0);
      }
    }
    float svr[4], tvr[4];
    #pragma unroll
    for (int r = 0; r < 4; ++r) {
      int node = min(v0 + q*4 + r, n-1);
      svr[r] = sv[node]; tvr[r] = tv[node];
    }
    #pragma unroll
    for (int t = 0; t < 8; ++t) {
      #pragma unroll
      for (int r = 0; r < 4; ++r) {
        int node = v0 + q*4 + r;
        if (node < n) {
          float m = fmaxf(acc[t][r] + t1[t].x*svr[r] + t1[t].y*tvr[r], 0.f);
          mu_s[(size_t)node*128 + t*16 + c] = f2bf(m);
        }
      }
    }
  }
}

// ------------------------------- CSR build ---------------------------------
__global__ void k_count(const int* __restrict__ src, int* __restrict__ cnt, int e) {
  int i = blockIdx.x*256 + threadIdx.x;
  if (i < e) atomicAdd(&cnt[src[i]], 1);
}

__global__ __launch_bounds__(256) void k_scan1(const int* __restrict__ cnt,
    int* __restrict__ excl, int* __restrict__ bsum, int n) {
  __shared__ int tmp[256];
  int tid = threadIdx.x;
  int i = blockIdx.x*256 + tid;
  int c = (i < n) ? cnt[i] : 0;
  tmp[tid] = c; __syncthreads();
  for (int off = 1; off < 256; off <<= 1) {
    int t = (tid >= off) ? tmp[tid - off] : 0;
    __syncthreads();
    tmp[tid] += t;
    __syncthreads();
  }
  if (i < n) excl[i] = tmp[tid] - c;
  if (tid == 255) bsum[blockIdx.x] = tmp[255];
}

__global__ __launch_bounds__(512) void k_scan2(const int* __restrict__ bsum,
    int* __restrict__ bbase, int nb) {
  __shared__ int tmp[512];
  int tid = threadIdx.x;
  int c = (tid < nb) ? bsum[tid] : 0;
  tmp[tid] = c; __syncthreads();
  for (int off = 1; off < 512; off <<= 1) {
    int t = (tid >= off) ? tmp[tid - off] : 0;
    __syncthreads();
    tmp[tid] += t;
    __syncthreads();
  }
  if (tid < nb) bbase[tid] = tmp[tid] - c;
}

__global__ void k_initcur(const int* __restrict__ excl, const int* __restrict__ bbase,
                          int* __restrict__ rowstart, int* __restrict__ cursor, int n) {
  int i = blockIdx.x*256 + threadIdx.x;
  if (i < n) { int r = excl[i] + bbase[i >> 8]; rowstart[i] = r; cursor[i] = r; }
}

__global__ void k_scatter(const int* __restrict__ src, const int* __restrict__ dst,
                          int* __restrict__ cursor, int* __restrict__ sorted, int e) {
  int i = blockIdx.x*256 + threadIdx.x;
  if (i < e) {
    int p = atomicAdd(&cursor[src[i]], 1);
    sorted[p] = dst[i];
  }
}

// ---------------------------------------------------------------------------
// Gather: rs[v] = relu(deg*mu[v] - sum_{u in N(v)} mu[u])  bf16 [N][128]
// Zero LDS (full occupancy); 8 independent row-loads in flight per batch.
// ---------------------------------------------------------------------------
__global__ __launch_bounds__(256) void k_gather(
    const uint* __restrict__ mu_u, const int* __restrict__ sorted,
    const int* __restrict__ cnt, const int* __restrict__ rowstart,
    uint* __restrict__ rs_u, int n)
{
  int w = threadIdx.x >> 6, l = threadIdx.x & 63;
  for (int v = blockIdx.x*4 + w; v < n; v += gridDim.x*4) {
    int deg = cnt[v], start = rowstart[v];
    float nb0 = 0.f, nb1 = 0.f;
    for (int base = 0; base < deg; base += 64) {
      int m = min(deg - base, 64);
      int idx = (l < m) ? sorted[start + base + l] : 0;
      int j = 0;
      for (; j + 8 <= m; j += 8) {
        uint u0 = mu_u[(size_t)__shfl(idx, j+0, 64)*64 + l];
        uint u1 = mu_u[(size_t)__shfl(idx, j+1, 64)*64 + l];
        uint u2 = mu_u[(size_t)__shfl(idx, j+2, 64)*64 + l];
        uint u3 = mu_u[(size_t)__shfl(idx, j+3, 64)*64 + l];
        uint u4 = mu_u[(size_t)__shfl(idx, j+4, 64)*64 + l];
        uint u5 = mu_u[(size_t)__shfl(idx, j+5, 64)*64 + l];
        uint u6 = mu_u[(size_t)__shfl(idx, j+6, 64)*64 + l];
        uint u7 = mu_u[(size_t)__shfl(idx, j+7, 64)*64 + l];
        nb0 += (bflo(u0)+bflo(u1)) + (bflo(u2)+bflo(u3))
             + (bflo(u4)+bflo(u5)) + (bflo(u6)+bflo(u7));
        nb1 += (bfhi(u0)+bfhi(u1)) + (bfhi(u2)+bfhi(u3))
             + (bfhi(u4)+bfhi(u5)) + (bfhi(u6)+bfhi(u7));
      }
      for (; j < m; ++j) {
        uint u = mu_u[(size_t)__shfl(idx, j, 64)*64 + l];
        nb0 += bflo(u); nb1 += bfhi(u);
      }
    }
    uint um = mu_u[(size_t)v*64 + l];
    float dg = (float)deg;
    float s0 = fmaxf(dg*bflo(um) - nb0, 0.f);
    float s1 = fmaxf(dg*bfhi(um) - nb1, 0.f);
    rs_u[(size_t)v*64 + l] = pack2(s0, s1);
  }
}

// ---------------------------------------------------------------------------
// MFMA GEMM #2: mu'[v] = [mu ; relu(s)] @ h_theta^T   (K=256, A split two bufs)
// ---------------------------------------------------------------------------
__global__ __launch_bounds__(256) void k_mlp(
    const uint4* __restrict__ mu4, const uint4* __restrict__ rs4,
    const float* __restrict__ hth, ushort* __restrict__ mup_s, int n)
{
  __shared__ uint4 B[4096];   // [s:8][t:8][lane:64], 64 KB
  const int tid = threadIdx.x;
  for (int f = tid; f < 4096; f += 256) {
    int l = f & 63, rest = f >> 6;          // 0..63
    int s = rest >> 3, t = rest & 7;
    int row = t*16 + (l & 15);
    int kb  = s*32 + (l >> 4)*8;
    const float* p = hth + row*256 + kb;
    float4 a = *(const float4*)p;
    float4 b = *(const float4*)(p + 4);
    uint4 u; u.x = pack2(a.x,a.y); u.y = pack2(a.z,a.w);
    u.z = pack2(b.x,b.y); u.w = pack2(b.z,b.w);
    B[(s*8 + t)*64 + l] = u;
  }
  __syncthreads();
  const int w = tid >> 6, l = tid & 63, q = l >> 4, c = l & 15;
  const int ntiles = (n + 15) >> 4;
  for (int T = blockIdx.x*4 + w; T < ntiles; T += gridDim.x*4) {
    int v0 = T*16;
    int arow = min(v0 + c, n-1);
    U4H8 a[8];
    #pragma unroll
    for (int s = 0; s < 4; ++s) a[s].u   = mu4[(size_t)arow*16 + s*4 + q];
    #pragma unroll
    for (int s = 0; s < 4; ++s) a[4+s].u = rs4[(size_t)arow*16 + s*4 + q];
    f32x4 acc[8];
    #pragma unroll
    for (int t = 0; t < 8; ++t) acc[t] = (f32x4){0.f,0.f,0.f,0.f};
    #pragma unroll
    for (int s = 0; s < 8; ++s) {
      #pragma unroll
      for (int t = 0; t < 8; ++t) {
        U4H8 b; b.u = B[(s*8 + t)*64 + l];
        acc[t] = __builtin_amdgcn_mfma_f32_16x16x32_bf16(a[s].h, b.h, acc[t], 0, 0, 0);
      }
    }
    #pragma unroll
    for (int t = 0; t < 8; ++t) {
      #pragma unroll
      for (int r = 0; r < 4; ++r) {
        int node = v0 + q*4 + r;
        if (node < n) mup_s[(size_t)node*128 + t*16 + c] = f2bf(acc[t][r]);
      }
    }
  }
}

// column sums of mu' -> gsum[128]
__global__ __launch_bounds__(256) void k_colsum(const uint* __restrict__ mup_u,
    float* __restrict__ gsum, int n) {
  int w = threadIdx.x >> 6, l = threadIdx.x & 63;
  float a0 = 0.f, a1 = 0.f;
  for (int v = blockIdx.x*4 + w; v < n; v += gridDim.x*4) {
    uint u = mup_u[(size_t)v*64 + l];
    a0 += bflo(u); a1 += bfhi(u);
  }
  atomicAdd(&gsum[2*l],   a0);
  atomicAdd(&gsum[2*l+1], a1);
}

// up = th4 @ gsum; C = sum_p th3[p]*relu(up[p])
__global__ __launch_bounds__(128) void k_upC(const float* __restrict__ gsum,
    const float* __restrict__ th4, const float* __restrict__ th3,
    float* __restrict__ Cbuf) {
  __shared__ float S[128];
  __shared__ float part[128];
  int tid = threadIdx.x;
  S[tid] = gsum[tid];
  __syncthreads();
  float up = 0.f;
  const float4* r4 = (const float4*)(th4 + tid*128);
  const float4* S4 = (const float4*)S;
  #pragma unroll 8
  for (int qq = 0; qq < 32; ++qq) {
    float4 wv = r4[qq], av = S4[qq];
    up += wv.x*av.x + wv.y*av.y + wv.z*av.z + wv.w*av.w;
  }
  float r = th3[tid] * fmaxf(up, 0.f);
  part[tid] = r; __syncthreads();
  if (tid < 64) part[tid] += part[tid + 64];
  __syncthreads();
  if (tid < 64) {
    float v = part[tid];
    #pragma unroll
    for (int off = 32; off > 0; off >>= 1) v += __shfl_down(v, off, 64);
    if (tid == 0) Cbuf[0] = v;
  }
}

// ---------------------------------------------------------------------------
// MFMA GEMM #3 + epilogue: out[v] = C + sum_p th3[128+p]*relu((mu' @ th5^T)[v][p])
// ---------------------------------------------------------------------------
__global__ __launch_bounds__(256) void k_final(
    const uint4* __restrict__ mup4, const float* __restrict__ th5,
    const float* __restrict__ th3, const float* __restrict__ Cbuf,
    float* __restrict__ out, int n)
{
  __shared__ uint4 B[2048];   // 32 KB
  const int tid = threadIdx.x;
  for (int f = tid; f < 2048; f += 256) {
    int l = f & 63, rest = f >> 6;
    int s = rest >> 3, t = rest & 7;
    int row = t*16 + (l & 15);
    int kb  = s*32 + (l >> 4)*8;
    const float* p = th5 + row*128 + kb;
    float4 a = *(const float4*)p;
    float4 b = *(const float4*)(p + 4);
    uint4 u; u.x = pack2(a.x,a.y); u.y = pack2(a.z,a.w);
    u.z = pack2(b.x,b.y); u.w = pack2(b.z,b.w);
    B[(s*8 + t)*64 + l] = u;
  }
  __syncthreads();
  const int w = tid >> 6, l = tid & 63, q = l >> 4, c = l & 15;
  float t3w[8];
  #pragma unroll
  for (int t = 0; t < 8; ++t) t3w[t] = th3[128 + t*16 + c];
  const float C = Cbuf[0];
  const int ntiles = (n + 15) >> 4;
  for (int T = blockIdx.x*4 + w; T < ntiles; T += gridDim.x*4) {
    int v0 = T*16;
    int arow = min(v0 + c, n-1);
    U4H8 a[4];
    #pragma unroll
    for (int s = 0; s < 4; ++s) a[s].u = mup4[(size_t)arow*16 + s*4 + q];
    f32x4 acc[8];
    #pragma unroll
    for (int t = 0; t < 8; ++t) acc[t] = (f32x4){0.f,0.f,0.f,0.f};
    #pragma unroll
    for (int s = 0; s < 4; ++s) {
      #pragma unroll
      for (int t = 0; t < 8; ++t) {
        U4H8 b; b.u = B[(s*8 + t)*64 + l];
        acc[t] = __builtin_amdgcn_mfma_f32_16x16x32_bf16(a[s].h, b.h, acc[t], 0, 0, 0);
      }
    }
    float red[4] = {0.f, 0.f, 0.f, 0.f};
    #pragma unroll
    for (int t = 0; t < 8; ++t) {
      #pragma unroll
      for (int r = 0; r < 4; ++r)
        red[r] += t3w[t] * fmaxf(acc[t][r], 0.f);
    }
    #pragma unroll
    for (int r = 0; r < 4; ++r) {
      #pragma unroll
      for (int off = 1; off < 16; off <<= 1)
        red[r] += __shfl_xor(red[r], off, 64);
    }
    if (c == 0) {
      #pragma unroll
      for (int r = 0; r < 4; ++r) {
        int node = v0 + q*4 + r;
        if (node < n) out[node] = C + red[r];
      }
    }
  }
}

extern "C" void kernel_launch(void* const* d_in, const int* in_sizes, int n_in,
                              void* d_out, int out_size, void* d_ws, size_t ws_size,
                              hipStream_t stream)
{
  const float* sv  = (const float*)d_in[0];
  const float* tv  = (const float*)d_in[1];
  const float* x   = (const float*)d_in[2];
  const int*   esrc= (const int*)d_in[3];
  const int*   edst= (const int*)d_in[4];
  const float* th1 = (const float*)d_in[5];
  const float* th2 = (const float*)d_in[6];
  const float* th3 = (const float*)d_in[7];
  const float* th4 = (const float*)d_in[8];
  const float* th5 = (const float*)d_in[9];
  const float* hth = (const float*)d_in[10];
  float* out = (float*)d_out;
  const int n = in_sizes[0];
  const int e = in_sizes[3];

  char* wp = (char*)d_ws;
  auto carve = [&](size_t bytes) { char* p = wp; wp += (bytes + 255) & ~(size_t)255; return p; };
  uint*   xn    = (uint*)  carve((size_t)n*128*2);  // xn bf16; later reused as mu' (aliased)
  ushort* mu_s  = (ushort*)carve((size_t)n*128*2);  // mu bf16 row-major
  ushort* rs_s  = (ushort*)carve((size_t)n*128*2);  // relu(s) bf16 row-major
  int*    sorted= (int*)   carve((size_t)e*4);
  int*    cnt   = (int*)   carve((size_t)n*4);
  int*    excl  = (int*)   carve((size_t)n*4);
  int*    rowst = (int*)   carve((size_t)n*4);
  int*    cursor= (int*)   carve((size_t)n*4);
  int*    bsum  = (int*)   carve(512*4);
  int*    bbase = (int*)   carve(512*4);
  float*  gsum  = (float*) carve(128*4);
  float*  Cbuf  = (float*) carve(256);

  ushort* mup_s = (ushort*)xn;   // alias: xn dead after k_mu

  const int nb1 = (n + 255) >> 8;

  hipMemsetAsync(cnt, 0, (size_t)n*4, stream);
  hipMemsetAsync(gsum, 0, 128*4, stream);

  k_norm   <<<1024, 256, 0, stream>>>(x, xn, n);
  k_mu     <<<1024, 256, 0, stream>>>((const uint4*)xn, sv, tv, th1, th2, mu_s, n);
  k_count  <<<(e + 255)/256, 256, 0, stream>>>(esrc, cnt, e);
  k_scan1  <<<nb1, 256, 0, stream>>>(cnt, excl, bsum, n);
  k_scan2  <<<1, 512, 0, stream>>>(bsum, bbase, nb1);
  k_initcur<<<nb1, 256, 0, stream>>>(excl, bbase, rowst, cursor, n);
  k_scatter<<<(e + 255)/256, 256, 0, stream>>>(esrc, edst, cursor, sorted, e);
  k_gather <<<2048, 256, 0, stream>>>((const uint*)mu_s, sorted, cnt, rowst,
                                      (uint*)rs_s, n);
  k_mlp    <<<1024, 256, 0, stream>>>((const uint4*)mu_s, (const uint4*)rs_s,
                                      hth, mup_s, n);
  k_colsum <<<256, 256, 0, stream>>>((const uint*)mup_s, gsum, n);
  k_upC    <<<1, 128, 0, stream>>>(gsum, th4, th3, Cbuf);
  k_final  <<<1024, 256, 0, stream>>>((const uint4*)mup_s, th5, th3, Cbuf, out, n);
}